// Round 14
// baseline (297.260 us; speedup 1.0000x reference)
//
#include <hip/hip_runtime.h>
#include <math.h>

typedef unsigned short u16;
typedef __attribute__((ext_vector_type(8))) short short8;
typedef __attribute__((ext_vector_type(8))) u16 u16x8;
typedef __attribute__((ext_vector_type(4))) float f32x4;

#define NTOK 16384   // B*S
#define DDIM 512
#define FDIM 2048
#define ENUM 8
#define NBLK 1024    // router/place blocks (16 tokens each)
#define APAD (32768 + 256)
#define NT1CAP 136   // sum ceil(cnt_e/256) <= 135
#define NT2CAP 264   // sum ceil(cnt_e/128) <= 263
#define G1GRID 1080  // 135 tiles * 8 ntiles (div by 8)
#define G2GRID 1056  // 264 * 4 ntiles (div by 8)

__device__ __forceinline__ u16 f2bf(float f) {
  unsigned u = __float_as_uint(f);
  u += 0x7FFFu + ((u >> 16) & 1u);   // RNE
  return (u16)(u >> 16);
}
__device__ __forceinline__ float bf2f(u16 b) {
  return __uint_as_float(((unsigned)b) << 16);
}

typedef const __attribute__((address_space(1))) unsigned int* gas1_t;
typedef __attribute__((address_space(3))) unsigned int* las3_t;
__device__ __forceinline__ void gload16(const u16* g, u16* l) {
  __builtin_amdgcn_global_load_lds((gas1_t)(const void*)g, (las3_t)(void*)l, 16, 0, 0);
}

// ---- prep: FUSED router (blocks 0..1023) + weight transpose (1024..5119) ---
__global__ __launch_bounds__(256) void prep_kernel(
    const float* __restrict__ x, const float* __restrict__ Wr,
    const float* __restrict__ br, int* __restrict__ top2e,
    float* __restrict__ top2v, int* __restrict__ histBase,
    float* __restrict__ gatePart, const float* __restrict__ W1,
    const float* __restrict__ W2, u16* __restrict__ W1T,
    u16* __restrict__ W2T) {
  __shared__ __align__(16) char smem[24704];
  int tid = threadIdx.x;
  if (blockIdx.x < NBLK) {
    float* sWr = (float*)smem;
    float(*sX)[DDIM] = (float(*)[DDIM])(smem + 16384);
    int* sHist = (int*)(smem + 16384 + 8192);
    float* sGate = (float*)(smem + 16384 + 8192 + 32);
    for (int i = tid; i < DDIM * ENUM; i += 256) sWr[i] = Wr[i];
    if (tid < ENUM) { sHist[tid] = 0; sGate[tid] = 0.f; }
    __syncthreads();
    int wave = tid >> 6, lane = tid & 63;
    int e = lane >> 3, dg = lane & 7;
    float bre = br[e];
    for (int it = 0; it < 4; ++it) {
      int t = blockIdx.x * 16 + wave * 4 + it;
      const float4* xr = (const float4*)(x + (size_t)t * DDIM);
      float4* sx4 = (float4*)sX[wave];
      sx4[lane] = xr[lane];
      sx4[lane + 64] = xr[lane + 64];
      asm volatile("s_waitcnt lgkmcnt(0)" ::: "memory");
      float acc = 0.f;
#pragma unroll 16
      for (int i = 0; i < 64; ++i) {
        float xv = sX[wave][i * 8 + dg];
        acc += xv * sWr[(i * 8 + dg) * 8 + e];
      }
      acc += __shfl_xor(acc, 1);
      acc += __shfl_xor(acc, 2);
      acc += __shfl_xor(acc, 4);
      float logit = acc + bre;
      float m = logit;
      m = fmaxf(m, __shfl_xor(m, 8));
      m = fmaxf(m, __shfl_xor(m, 16));
      m = fmaxf(m, __shfl_xor(m, 32));
      float pv = expf(logit - m);
      float s = pv;
      s += __shfl_xor(s, 8);
      s += __shfl_xor(s, 16);
      s += __shfl_xor(s, 32);
      float gate = pv / s;
      float v1 = gate; int i1 = e;
#pragma unroll
      for (int msk = 8; msk <= 32; msk <<= 1) {
        float ov = __shfl_xor(v1, msk);
        int oi = __shfl_xor(i1, msk);
        if (ov > v1 || (ov == v1 && oi < i1)) { v1 = ov; i1 = oi; }
      }
      float g2 = (e == i1) ? -1.f : gate;
      float v2 = g2; int i2 = e;
#pragma unroll
      for (int msk = 8; msk <= 32; msk <<= 1) {
        float ov = __shfl_xor(v2, msk);
        int oi = __shfl_xor(i2, msk);
        if (ov > v2 || (ov == v2 && oi < i2)) { v2 = ov; i2 = oi; }
      }
      if (lane == 0) {
        top2e[2 * t] = i1; top2e[2 * t + 1] = i2;
        top2v[2 * t] = v1; top2v[2 * t + 1] = v2;
        atomicAdd(&sHist[i1], 1);
        atomicAdd(&sHist[i2], 1);
      }
      if (dg == 0) atomicAdd(&sGate[e], gate);
    }
    __syncthreads();
    if (tid < ENUM) {
      histBase[blockIdx.x * 8 + tid] = sHist[tid];
      gatePart[blockIdx.x * 8 + tid] = sGate[tid];
    }
  } else {
    float(*tile)[65] = (float(*)[65])smem;
    int idx = blockIdx.x - NBLK;
    int by = idx >> 8, bx = idx & 255;
    int half = by >> 3, e = by & 7;
    const float* W = half ? W2 : W1;
    u16* WT = half ? W2T : W1T;
    int K = half ? FDIM : DDIM, N = half ? DDIM : FDIM;
    int tnc = N >> 6;
    int tk = bx / tnc, tn = bx - tk * tnc;
    const float* Wp = W + (size_t)e * K * N + (size_t)(tk * 64) * N + tn * 64;
#pragma unroll
    for (int i = 0; i < 4; ++i) {
      int row = (tid >> 4) + i * 16, c4 = (tid & 15) * 4;
      float4 v = *(const float4*)(Wp + (size_t)row * N + c4);
      tile[row][c4] = v.x; tile[row][c4 + 1] = v.y;
      tile[row][c4 + 2] = v.z; tile[row][c4 + 3] = v.w;
    }
    __syncthreads();
    u16* WTp = WT + (size_t)e * N * K + (size_t)(tn * 64) * K + tk * 64;
#pragma unroll
    for (int p = 0; p < 2; ++p) {
      int n = (tid >> 3) + p * 32, k0 = (tid & 7) * 8;
      u16x8 o;
#pragma unroll
      for (int j = 0; j < 8; ++j) o[j] = f2bf(tile[k0 + j][n]);
      *(u16x8*)(WTp + (size_t)n * K + k0) = o;
    }
  }
}

// ------- scan: bases, offsets, BOTH tile tables (256-row & 128-row), aux ----
__global__ __launch_bounds__(256) void scan_kernel(
    int* __restrict__ histBase, const float* __restrict__ gatePart,
    int* __restrict__ offsets, int* __restrict__ counts,
    int* __restrict__ tileE1, int* __restrict__ tileM1,
    int* __restrict__ tileE2, int* __restrict__ tileM2,
    int* __restrict__ nT, float* __restrict__ auxOut) {
  __shared__ int sTot[ENUM];
  __shared__ float sG[ENUM];
  int tid = threadIdx.x, wave = tid >> 6, lane = tid & 63;
  if (tid < ENUM) sG[tid] = 0.f;
  __syncthreads();
  float loc[8] = {0, 0, 0, 0, 0, 0, 0, 0};
  for (int r = tid; r < NBLK; r += 256) {
#pragma unroll
    for (int e = 0; e < 8; ++e) loc[e] += gatePart[r * 8 + e];
  }
#pragma unroll
  for (int e = 0; e < 8; ++e) atomicAdd(&sG[e], loc[e]);
#pragma unroll
  for (int ei = 0; ei < 2; ++ei) {
    int e = wave * 2 + ei;
    int running = 0;
    for (int itb = 0; itb < NBLK / 64; ++itb) {
      int idx = (itb * 64 + lane) * 8 + e;
      int v = histBase[idx];
      int inc = v;
#pragma unroll
      for (int d = 1; d < 64; d <<= 1) {
        int o = __shfl_up(inc, d);
        if (lane >= d) inc += o;
      }
      histBase[idx] = running + inc - v;
      running += __shfl(inc, 63);
    }
    if (lane == 0) sTot[e] = running;
  }
  __syncthreads();
  if (tid == 0) {
    int off = 0, nt1 = 0, nt2 = 0;
#pragma unroll
    for (int e = 0; e < 8; ++e) {
      int c = sTot[e];
      offsets[e] = off; counts[e] = c; off += c;
      int mt1 = (c + 255) >> 8;
      for (int m = 0; m < mt1; ++m) { tileE1[nt1] = e; tileM1[nt1] = m; ++nt1; }
      int mt2 = (c + 127) >> 7;
      for (int m = 0; m < mt2; ++m) { tileE2[nt2] = e; tileM2[nt2] = m; ++nt2; }
    }
    nT[0] = nt1; nT[1] = nt2;
    float aux = 0.f;
#pragma unroll
    for (int e = 0; e < 8; ++e) {
      float pr = sG[e] / (float)NTOK;
      aux += pr * logf(pr + 1e-9f);
    }
    *auxOut = aux;
  }
}

// ---------------- place: deterministic ranks + gathered bf16 X + tokA -------
__global__ __launch_bounds__(256) void place_kernel(
    const float* __restrict__ x, const int* __restrict__ top2e,
    const float* __restrict__ top2v, const int* __restrict__ histBase,
    const int* __restrict__ offsets, int* __restrict__ tokA,
    float* __restrict__ assignW, u16* __restrict__ Xg) {
  __shared__ int sA[32];
  int tid = threadIdx.x, wave = tid >> 6, lane = tid & 63;
  int blk = blockIdx.x;
  if (tid < 32) {
    int slot = tid;
    int t = blk * 16 + (slot >> 1);
    int e = top2e[2 * t + (slot & 1)];
    float v = top2v[2 * t + (slot & 1)];
    int rank = 0;
#pragma unroll
    for (int ee = 0; ee < 8; ++ee) {
      unsigned long long mm = __ballot(e == ee);
      if (e == ee) rank = __popcll(mm & ((1ull << slot) - 1));
    }
    int a = offsets[e] + histBase[blk * 8 + e] + rank;
    sA[slot] = a;
    tokA[2 * t + (slot & 1)] = a;   // token -> assignment (for combine)
    assignW[a] = v;
  }
  __syncthreads();
  for (int it = 0; it < 4; ++it) {
    int lt = wave * 4 + it;
    int t = blk * 16 + lt;
    const float4* xr = (const float4*)(x + (size_t)t * DDIM);
    float4 v0 = xr[lane * 2], v1 = xr[lane * 2 + 1];
    u16x8 o;
    o[0] = f2bf(v0.x); o[1] = f2bf(v0.y); o[2] = f2bf(v0.z); o[3] = f2bf(v0.w);
    o[4] = f2bf(v1.x); o[5] = f2bf(v1.y); o[6] = f2bf(v1.z); o[7] = f2bf(v1.w);
    int a1 = sA[2 * lt], a2 = sA[2 * lt + 1];
    *(u16x8*)(Xg + (size_t)a1 * DDIM + lane * 8) = o;
    *(u16x8*)(Xg + (size_t)a2 * DDIM + lane * 8) = o;
  }
}

// ========== GEMM1 mainloop: 256x256 tile, 512 thr / 8 waves (2m x 4n), ======
// ========== wave-tile 128x64 (acc 8x4), BK=32, ring-of-3 32KB units, ========
// ========== 96KB dynamic LDS (1 block/CU BY DESIGN), counted vmcnt(4) =======
// Intensity: 12 ds_read_b128 -> 32 MFMA per wave-phase (0.375 KB/MFMA vs
// r10's 0.5). Per-SIMD: 2 waves x 32 MFMA ~ 307 cyc vs LDS ~500 cyc ->
// ~60% ceiling (m201-validated geometry). r11/r12 failed this intensity at
// 256 thr (1 wave/SIMD, nothing to overlap); 512 thr gives 2/SIMD.
// Unit s (32KB at s*32768): A 256 rows x 64B at 0; B 256 rows x 64B at 16384.
// Stage: 4 gload16/thread (A c0,c1; B c0,c1; chunk c: row=c>>2,
// kslot=(c&3)^((c>>3)&3) pre-swizzled in global src). Gate vmcnt(4):
// outstanding = unit(t+1).4 + unit(t+2).4 = 8 -> retires exactly t+1.
template <int K>
__device__ __forceinline__ void mainloop8W(
    const u16* __restrict__ aG0, const u16* __restrict__ aG1,
    const u16* __restrict__ bG0, const u16* __restrict__ bG1,
    char* ldsB, f32x4 (&acc)[8][4]) {
  const int tid = threadIdx.x;
  const int lane = tid & 63, wave = tid >> 6;
  const int wr = wave >> 2, wc = wave & 3;
  const int fr = lane & 15;
  const int slotx = ((lane >> 4) ^ ((lane >> 1) & 3)) & 3;
  const int frA = (wr * 128 + fr) * 64 + slotx * 16;           // + m*1024
  const int frB = 16384 + (wc * 64 + fr) * 64 + slotx * 16;    // + n*1024
  const int w1024 = wave * 1024;
  const int KT = K / 32;

  auto STAGE = [&](int u, int s) {
    const size_t go = (size_t)u * 32;
    char* base = ldsB + s * 32768 + w1024;
    gload16(aG0 + go, (u16*)base);                    // A chunks 0..511
    gload16(aG1 + go, (u16*)(base + 8192));           // A chunks 512..1023
    gload16(bG0 + go, (u16*)(base + 16384));          // B chunks 0..511
    gload16(bG1 + go, (u16*)(base + 16384 + 8192));   // B chunks 512..1023
  };

  STAGE(0, 0);
  STAGE(1, 1);
  asm volatile("s_waitcnt vmcnt(4)" ::: "memory");
  __builtin_amdgcn_s_barrier();
  __builtin_amdgcn_sched_barrier(0);

  int s0 = 0, s1 = 1, s2 = 2;
#pragma unroll 1
  for (int t = 0; t < KT; ++t) {
    const char* cb = ldsB + s0 * 32768;
    short8 af[8], bf[4];
#pragma unroll
    for (int m = 0; m < 8; ++m)
      af[m] = *(const short8*)(cb + frA + m * 1024);
#pragma unroll
    for (int n = 0; n < 4; ++n)
      bf[n] = *(const short8*)(cb + frB + n * 1024);
    STAGE((t + 2) & (KT - 1), s2);
    asm volatile("s_waitcnt vmcnt(4)" ::: "memory");
    __builtin_amdgcn_s_barrier();
    __builtin_amdgcn_sched_barrier(0);
    __builtin_amdgcn_s_setprio(1);
#pragma unroll
    for (int m = 0; m < 8; ++m)
#pragma unroll
      for (int n = 0; n < 4; ++n)
        acc[m][n] = __builtin_amdgcn_mfma_f32_16x16x32_bf16(af[m], bf[n],
                                                            acc[m][n], 0, 0, 0);
    __builtin_amdgcn_s_setprio(0);
    __builtin_amdgcn_s_barrier();
    __builtin_amdgcn_sched_barrier(0);
    int tmp = s0; s0 = s1; s1 = s2; s2 = tmp;
  }
}

// ---------------- GEMM1: h = relu(Xg @ W1 + b1), bf16 out -------------------
__global__ __launch_bounds__(512) void gemm1_kernel(
    const u16* __restrict__ Xg, const u16* __restrict__ W1T,
    const float* __restrict__ b1, u16* __restrict__ h,
    const int* __restrict__ counts, const int* __restrict__ offsets,
    const int* __restrict__ tileE1, const int* __restrict__ tileM1,
    const int* __restrict__ nT) {
  extern __shared__ char ldsB[];
  int wg = blockIdx.x;
  int L = (wg & 7) * (G1GRID / 8) + (wg >> 3);   // XCD-chunked, ntile fastest
  int tile = L >> 3, ntile = L & 7;
  if (tile >= nT[0]) return;
  int e = tileE1[tile], mtile = tileM1[tile];
  int cnt = counts[e], off = offsets[e];
  int tid = threadIdx.x;
  int r0 = tid >> 2;                                  // 0..127
  int cswz = ((tid & 3) ^ ((tid >> 3) & 3)) * 8;      // u16 elements
  const u16* Ap = Xg + (size_t)(off + mtile * 256) * DDIM;
  const u16* aG0 = Ap + (size_t)r0 * DDIM + cswz;
  const u16* aG1 = Ap + (size_t)(r0 + 128) * DDIM + cswz;
  const u16* Bp = W1T + ((size_t)e * FDIM + ntile * 256) * DDIM;
  const u16* bG0 = Bp + (size_t)r0 * DDIM + cswz;
  const u16* bG1 = Bp + (size_t)(r0 + 128) * DDIM + cswz;
  f32x4 acc[8][4] = {};
  mainloop8W<DDIM>(aG0, aG1, bG0, bG1, ldsB, acc);
  int lane = tid & 63, wave = tid >> 6;
  int wr = wave >> 2, wc = wave & 3;
  int cl = lane & 15, rq = (lane >> 4) * 4;
#pragma unroll
  for (int m = 0; m < 8; ++m) {
#pragma unroll
    for (int i = 0; i < 4; ++i) {
      int gr = mtile * 256 + wr * 128 + m * 16 + rq + i;
      if (gr < cnt) {
#pragma unroll
        for (int n = 0; n < 4; ++n) {
          int gc = ntile * 256 + wc * 64 + n * 16 + cl;
          float v = acc[m][n][i] + b1[e * FDIM + gc];
          v = fmaxf(v, 0.f);
          h[(size_t)(off + gr) * FDIM + gc] = f2bf(v);
        }
      }
    }
  }
}

// ========== GEMM2 mainloop (r10/r13, proven): 128x128, 4 waves, ring-3 ======
template <int K>
__device__ __forceinline__ void mainloopR(
    const u16* __restrict__ aG0, const u16* __restrict__ aG1,
    const u16* __restrict__ bG0, const u16* __restrict__ bG1,
    char* ldsB, f32x4 (&acc)[4][4]) {
  const int tid = threadIdx.x;
  const int lane = tid & 63, wave = tid >> 6;
  const int wr = wave >> 1, wc = wave & 1;
  const int fr = lane & 15;
  const int slotx = ((lane >> 4) ^ ((lane >> 1) & 3)) & 3;
  const int frA = wr * 4096 + fr * 64 + slotx * 16;
  const int frB = 8192 + wc * 4096 + fr * 64 + slotx * 16;
  const int w1024 = wave * 1024;
  const int KT = K / 32;

  auto STAGE = [&](int u, int s) {
    const size_t go = (size_t)u * 32;
    char* base = ldsB + s * 16384 + w1024;
    gload16(aG0 + go, (u16*)base);
    gload16(aG1 + go, (u16*)(base + 4096));
    gload16(bG0 + go, (u16*)(base + 8192));
    gload16(bG1 + go, (u16*)(base + 8192 + 4096));
  };

  STAGE(0, 0);
  STAGE(1, 1);
  asm volatile("s_waitcnt vmcnt(4)" ::: "memory");
  __builtin_amdgcn_s_barrier();
  __builtin_amdgcn_sched_barrier(0);

  int s0 = 0, s1 = 1, s2 = 2;
#pragma unroll 1
  for (int t = 0; t < KT; ++t) {
    const char* cb = ldsB + s0 * 16384;
    short8 af[4], bf[4];
#pragma unroll
    for (int m = 0; m < 4; ++m)
      af[m] = *(const short8*)(cb + frA + m * 1024);
#pragma unroll
    for (int n = 0; n < 4; ++n)
      bf[n] = *(const short8*)(cb + frB + n * 1024);
    STAGE((t + 2) & (KT - 1), s2);
    asm volatile("s_waitcnt vmcnt(4)" ::: "memory");
    __builtin_amdgcn_s_barrier();
    __builtin_amdgcn_sched_barrier(0);
    __builtin_amdgcn_s_setprio(1);
#pragma unroll
    for (int m = 0; m < 4; ++m)
#pragma unroll
      for (int n = 0; n < 4; ++n)
        acc[m][n] = __builtin_amdgcn_mfma_f32_16x16x32_bf16(af[m], bf[n],
                                                            acc[m][n], 0, 0, 0);
    __builtin_amdgcn_s_setprio(0);
    __builtin_amdgcn_s_barrier();
    __builtin_amdgcn_sched_barrier(0);
    int tmp = s0; s0 = s1; s1 = s2; s2 = tmp;
  }
}

// ---------------- GEMM2: z[a] = w_a * (h @ W2 + b2), bf16 -------------------
__global__ __launch_bounds__(256) void gemm2_kernel(
    const u16* __restrict__ h, const u16* __restrict__ W2T,
    const float* __restrict__ b2, const float* __restrict__ assignW,
    const int* __restrict__ counts, const int* __restrict__ offsets,
    const int* __restrict__ tileE2, const int* __restrict__ tileM2,
    const int* __restrict__ nT, u16* __restrict__ z) {
  __shared__ __align__(16) char ldsB[49152];
  int wg = blockIdx.x;
  int L = (wg & 7) * (G2GRID / 8) + (wg >> 3);
  int tile = L >> 2, ntile = L & 3;
  if (tile >= nT[1]) return;
  int e = tileE2[tile], mtile = tileM2[tile];
  int cnt = counts[e], off = offsets[e];
  int tid = threadIdx.x;
  int r0 = tid >> 2;
  int cswz = ((tid & 3) ^ ((tid >> 3) & 3)) * 8;
  const u16* Ap = h + (size_t)(off + mtile * 128) * FDIM;
  const u16* aG0 = Ap + (size_t)r0 * FDIM + cswz;
  const u16* aG1 = Ap + (size_t)(r0 + 64) * FDIM + cswz;
  const u16* Bp = W2T + ((size_t)e * DDIM + ntile * 128) * FDIM;
  const u16* bG0 = Bp + (size_t)r0 * FDIM + cswz;
  const u16* bG1 = Bp + (size_t)(r0 + 64) * FDIM + cswz;
  f32x4 acc[4][4] = {};
  mainloopR<FDIM>(aG0, aG1, bG0, bG1, ldsB, acc);
  int lane = tid & 63, wave = tid >> 6;
  int wr = wave >> 1, wc = wave & 1;
  int cl = lane & 15, rq = (lane >> 4) * 4;
#pragma unroll
  for (int m = 0; m < 4; ++m) {
#pragma unroll
    for (int i = 0; i < 4; ++i) {
      int gr = mtile * 128 + wr * 64 + m * 16 + rq + i;
      if (gr < cnt) {
        int a = off + gr;
        float w = assignW[a];
#pragma unroll
        for (int n = 0; n < 4; ++n) {
          int gc = ntile * 128 + wc * 64 + n * 16 + cl;
          float v = (acc[m][n][i] + b2[e * DDIM + gc]) * w;
          z[(size_t)a * DDIM + gc] = f2bf(v);
        }
      }
    }
  }
}

// ---------------- combine: out[t] = z[a1(t)] + z[a2(t)] ---------------------
__global__ __launch_bounds__(256) void combine_kernel(
    const u16* __restrict__ z, const int* __restrict__ tokA,
    float* __restrict__ out) {
  int tid = threadIdx.x, wave = tid >> 6, lane = tid & 63;
  int t = blockIdx.x * 4 + wave;
  int a1 = tokA[2 * t], a2 = tokA[2 * t + 1];
  u16x8 v1 = *(const u16x8*)(z + (size_t)a1 * DDIM + lane * 8);
  u16x8 v2 = *(const u16x8*)(z + (size_t)a2 * DDIM + lane * 8);
  float4 o0, o1;
  o0.x = bf2f(v1[0]) + bf2f(v2[0]);
  o0.y = bf2f(v1[1]) + bf2f(v2[1]);
  o0.z = bf2f(v1[2]) + bf2f(v2[2]);
  o0.w = bf2f(v1[3]) + bf2f(v2[3]);
  o1.x = bf2f(v1[4]) + bf2f(v2[4]);
  o1.y = bf2f(v1[5]) + bf2f(v2[5]);
  o1.z = bf2f(v1[6]) + bf2f(v2[6]);
  o1.w = bf2f(v1[7]) + bf2f(v2[7]);
  float4* o = (float4*)(out + (size_t)t * DDIM + lane * 8);
  o[0] = o0;
  o[1] = o1;
}

extern "C" void kernel_launch(void* const* d_in, const int* in_sizes, int n_in,
                              void* d_out, int out_size, void* d_ws, size_t ws_size,
                              hipStream_t stream) {
  const float* x  = (const float*)d_in[0];
  const float* Wr = (const float*)d_in[1];
  const float* br = (const float*)d_in[2];
  const float* W1 = (const float*)d_in[3];
  const float* b1 = (const float*)d_in[4];
  const float* W2 = (const float*)d_in[5];
  const float* b2 = (const float*)d_in[6];
  float* out = (float*)d_out;

  char* ws = (char*)d_ws;
  size_t p = 0;
  auto alloc = [&](size_t bytes) -> void* {
    void* r = ws + p;
    p = (p + bytes + 255) & ~(size_t)255;
    return r;
  };
  int* counts     = (int*)alloc(ENUM * 4);
  int* offsets    = (int*)alloc(ENUM * 4);
  int* nT         = (int*)alloc(2 * 4);
  int* tileE1     = (int*)alloc(NT1CAP * 4);
  int* tileM1     = (int*)alloc(NT1CAP * 4);
  int* tileE2     = (int*)alloc(NT2CAP * 4);
  int* tileM2     = (int*)alloc(NT2CAP * 4);
  int* top2e      = (int*)alloc((size_t)NTOK * 2 * 4);
  float* top2v    = (float*)alloc((size_t)NTOK * 2 * 4);
  int* tokA       = (int*)alloc((size_t)NTOK * 2 * 4);  // token -> assignment
  float* assignW  = (float*)alloc((size_t)APAD * 4);
  int* histBase   = (int*)alloc((size_t)NBLK * 8 * 4);
  float* gatePart = (float*)alloc((size_t)NBLK * 8 * 4);
  u16* W1T        = (u16*)alloc((size_t)ENUM * FDIM * DDIM * 2);
  u16* W2T        = (u16*)alloc((size_t)ENUM * DDIM * FDIM * 2);
  u16* Xg         = (u16*)alloc((size_t)APAD * DDIM * 2);
  u16* hbuf       = (u16*)alloc((size_t)APAD * FDIM * 2);
  u16* z          = Xg;   // alias: Xg dead after gemm1
  (void)in_sizes; (void)n_in; (void)out_size; (void)ws_size;  // ~203 MB used

  (void)hipFuncSetAttribute((const void*)gemm1_kernel,
                            hipFuncAttributeMaxDynamicSharedMemorySize, 98304);

  prep_kernel<<<NBLK + 4096, 256, 0, stream>>>(x, Wr, br, top2e, top2v,
                                               histBase, gatePart, W1, W2,
                                               W1T, W2T);
  scan_kernel<<<1, 256, 0, stream>>>(histBase, gatePart, offsets, counts,
                                     tileE1, tileM1, tileE2, tileM2, nT,
                                     out + (size_t)NTOK * DDIM);
  place_kernel<<<NBLK, 256, 0, stream>>>(x, top2e, top2v, histBase, offsets,
                                         tokA, assignW, Xg);
  gemm1_kernel<<<G1GRID, 512, 98304, stream>>>(
      Xg, W1T, b1, hbuf, counts, offsets, tileE1, tileM1, nT);
  gemm2_kernel<<<G2GRID, 256, 0, stream>>>(
      hbuf, W2T, b2, assignW, counts, offsets, tileE2, tileM2, nT, z);
  combine_kernel<<<NTOK / 4, 256, 0, stream>>>(z, tokA, out);
}

// Round 15
// 282.862 us; speedup vs baseline: 1.0509x; 1.0509x over previous
//
#include <hip/hip_runtime.h>
#include <math.h>

typedef unsigned short u16;
typedef __attribute__((ext_vector_type(8))) short short8;
typedef __attribute__((ext_vector_type(8))) u16 u16x8;
typedef __attribute__((ext_vector_type(4))) float f32x4;

#define NTOK 16384   // B*S
#define DDIM 512
#define FDIM 2048
#define ENUM 8
#define NBLK 1024    // router/place blocks (16 tokens each)
#define APAD (32768 + 256)
#define NTCAP 264    // sum ceil(cnt_e/128) <= 263
#define G1GRID 4224  // 264 * 16 ntiles (div by 8)
#define G2GRID 1056  // 264 * 4 ntiles  (div by 8)

__device__ __forceinline__ u16 f2bf(float f) {
  unsigned u = __float_as_uint(f);
  u += 0x7FFFu + ((u >> 16) & 1u);   // RNE
  return (u16)(u >> 16);
}
__device__ __forceinline__ float bf2f(u16 b) {
  return __uint_as_float(((unsigned)b) << 16);
}

typedef const __attribute__((address_space(1))) unsigned int* gas1_t;
typedef __attribute__((address_space(3))) unsigned int* las3_t;
__device__ __forceinline__ void gload16(const u16* g, u16* l) {
  __builtin_amdgcn_global_load_lds((gas1_t)(const void*)g, (las3_t)(void*)l, 16, 0, 0);
}

// ---- prep: FUSED router (blocks 0..1023) + weight transpose (1024..5119) ---
__global__ __launch_bounds__(256) void prep_kernel(
    const float* __restrict__ x, const float* __restrict__ Wr,
    const float* __restrict__ br, int* __restrict__ top2e,
    float* __restrict__ top2v, int* __restrict__ histBase,
    float* __restrict__ gatePart, const float* __restrict__ W1,
    const float* __restrict__ W2, u16* __restrict__ W1T,
    u16* __restrict__ W2T) {
  __shared__ __align__(16) char smem[24704];
  int tid = threadIdx.x;
  if (blockIdx.x < NBLK) {
    float* sWr = (float*)smem;
    float(*sX)[DDIM] = (float(*)[DDIM])(smem + 16384);
    int* sHist = (int*)(smem + 16384 + 8192);
    float* sGate = (float*)(smem + 16384 + 8192 + 32);
    for (int i = tid; i < DDIM * ENUM; i += 256) sWr[i] = Wr[i];
    if (tid < ENUM) { sHist[tid] = 0; sGate[tid] = 0.f; }
    __syncthreads();
    int wave = tid >> 6, lane = tid & 63;
    int e = lane >> 3, dg = lane & 7;
    float bre = br[e];
    for (int it = 0; it < 4; ++it) {
      int t = blockIdx.x * 16 + wave * 4 + it;
      const float4* xr = (const float4*)(x + (size_t)t * DDIM);
      float4* sx4 = (float4*)sX[wave];
      sx4[lane] = xr[lane];
      sx4[lane + 64] = xr[lane + 64];
      asm volatile("s_waitcnt lgkmcnt(0)" ::: "memory");
      float acc = 0.f;
#pragma unroll 16
      for (int i = 0; i < 64; ++i) {
        float xv = sX[wave][i * 8 + dg];
        acc += xv * sWr[(i * 8 + dg) * 8 + e];
      }
      acc += __shfl_xor(acc, 1);
      acc += __shfl_xor(acc, 2);
      acc += __shfl_xor(acc, 4);
      float logit = acc + bre;
      float m = logit;
      m = fmaxf(m, __shfl_xor(m, 8));
      m = fmaxf(m, __shfl_xor(m, 16));
      m = fmaxf(m, __shfl_xor(m, 32));
      float pv = expf(logit - m);
      float s = pv;
      s += __shfl_xor(s, 8);
      s += __shfl_xor(s, 16);
      s += __shfl_xor(s, 32);
      float gate = pv / s;
      float v1 = gate; int i1 = e;
#pragma unroll
      for (int msk = 8; msk <= 32; msk <<= 1) {
        float ov = __shfl_xor(v1, msk);
        int oi = __shfl_xor(i1, msk);
        if (ov > v1 || (ov == v1 && oi < i1)) { v1 = ov; i1 = oi; }
      }
      float g2 = (e == i1) ? -1.f : gate;
      float v2 = g2; int i2 = e;
#pragma unroll
      for (int msk = 8; msk <= 32; msk <<= 1) {
        float ov = __shfl_xor(v2, msk);
        int oi = __shfl_xor(i2, msk);
        if (ov > v2 || (ov == v2 && oi < i2)) { v2 = ov; i2 = oi; }
      }
      if (lane == 0) {
        top2e[2 * t] = i1; top2e[2 * t + 1] = i2;
        top2v[2 * t] = v1; top2v[2 * t + 1] = v2;
        atomicAdd(&sHist[i1], 1);
        atomicAdd(&sHist[i2], 1);
      }
      if (dg == 0) atomicAdd(&sGate[e], gate);
    }
    __syncthreads();
    if (tid < ENUM) {
      histBase[blockIdx.x * 8 + tid] = sHist[tid];
      gatePart[blockIdx.x * 8 + tid] = sGate[tid];
    }
  } else {
    float(*tile)[65] = (float(*)[65])smem;
    int idx = blockIdx.x - NBLK;
    int by = idx >> 8, bx = idx & 255;
    int half = by >> 3, e = by & 7;
    const float* W = half ? W2 : W1;
    u16* WT = half ? W2T : W1T;
    int K = half ? FDIM : DDIM, N = half ? DDIM : FDIM;
    int tnc = N >> 6;
    int tk = bx / tnc, tn = bx - tk * tnc;
    const float* Wp = W + (size_t)e * K * N + (size_t)(tk * 64) * N + tn * 64;
#pragma unroll
    for (int i = 0; i < 4; ++i) {
      int row = (tid >> 4) + i * 16, c4 = (tid & 15) * 4;
      float4 v = *(const float4*)(Wp + (size_t)row * N + c4);
      tile[row][c4] = v.x; tile[row][c4 + 1] = v.y;
      tile[row][c4 + 2] = v.z; tile[row][c4 + 3] = v.w;
    }
    __syncthreads();
    u16* WTp = WT + (size_t)e * N * K + (size_t)(tn * 64) * K + tk * 64;
#pragma unroll
    for (int p = 0; p < 2; ++p) {
      int n = (tid >> 3) + p * 32, k0 = (tid & 7) * 8;
      u16x8 o;
#pragma unroll
      for (int j = 0; j < 8; ++j) o[j] = f2bf(tile[k0 + j][n]);
      *(u16x8*)(WTp + (size_t)n * K + k0) = o;
    }
  }
}

// ---------------- scan: bases, offsets, 128-row tile table, aux -------------
__global__ __launch_bounds__(256) void scan_kernel(
    int* __restrict__ histBase, const float* __restrict__ gatePart,
    int* __restrict__ offsets, int* __restrict__ counts,
    int* __restrict__ tileE, int* __restrict__ tileM, int* __restrict__ nT,
    float* __restrict__ auxOut) {
  __shared__ int sTot[ENUM];
  __shared__ float sG[ENUM];
  int tid = threadIdx.x, wave = tid >> 6, lane = tid & 63;
  if (tid < ENUM) sG[tid] = 0.f;
  __syncthreads();
  float loc[8] = {0, 0, 0, 0, 0, 0, 0, 0};
  for (int r = tid; r < NBLK; r += 256) {
#pragma unroll
    for (int e = 0; e < 8; ++e) loc[e] += gatePart[r * 8 + e];
  }
#pragma unroll
  for (int e = 0; e < 8; ++e) atomicAdd(&sG[e], loc[e]);
#pragma unroll
  for (int ei = 0; ei < 2; ++ei) {
    int e = wave * 2 + ei;
    int running = 0;
    for (int itb = 0; itb < NBLK / 64; ++itb) {
      int idx = (itb * 64 + lane) * 8 + e;
      int v = histBase[idx];
      int inc = v;
#pragma unroll
      for (int d = 1; d < 64; d <<= 1) {
        int o = __shfl_up(inc, d);
        if (lane >= d) inc += o;
      }
      histBase[idx] = running + inc - v;
      running += __shfl(inc, 63);
    }
    if (lane == 0) sTot[e] = running;
  }
  __syncthreads();
  if (tid == 0) {
    int off = 0, nt = 0;
#pragma unroll
    for (int e = 0; e < 8; ++e) {
      int c = sTot[e];
      offsets[e] = off; counts[e] = c; off += c;
      int mt = (c + 127) >> 7;
      for (int m = 0; m < mt; ++m) { tileE[nt] = e; tileM[nt] = m; ++nt; }
    }
    nT[0] = nt;
    float aux = 0.f;
#pragma unroll
    for (int e = 0; e < 8; ++e) {
      float pr = sG[e] / (float)NTOK;
      aux += pr * logf(pr + 1e-9f);
    }
    *auxOut = aux;
  }
}

// ---------------- place: deterministic ranks + gathered bf16 X + tokA -------
__global__ __launch_bounds__(256) void place_kernel(
    const float* __restrict__ x, const int* __restrict__ top2e,
    const float* __restrict__ top2v, const int* __restrict__ histBase,
    const int* __restrict__ offsets, int* __restrict__ tokA,
    float* __restrict__ assignW, u16* __restrict__ Xg) {
  __shared__ int sA[32];
  int tid = threadIdx.x, wave = tid >> 6, lane = tid & 63;
  int blk = blockIdx.x;
  if (tid < 32) {
    int slot = tid;
    int t = blk * 16 + (slot >> 1);
    int e = top2e[2 * t + (slot & 1)];
    float v = top2v[2 * t + (slot & 1)];
    int rank = 0;
#pragma unroll
    for (int ee = 0; ee < 8; ++ee) {
      unsigned long long mm = __ballot(e == ee);
      if (e == ee) rank = __popcll(mm & ((1ull << slot) - 1));
    }
    int a = offsets[e] + histBase[blk * 8 + e] + rank;
    sA[slot] = a;
    tokA[2 * t + (slot & 1)] = a;   // token -> assignment (for combine)
    assignW[a] = v;
  }
  __syncthreads();
  for (int it = 0; it < 4; ++it) {
    int lt = wave * 4 + it;
    int t = blk * 16 + lt;
    const float4* xr = (const float4*)(x + (size_t)t * DDIM);
    float4 v0 = xr[lane * 2], v1 = xr[lane * 2 + 1];
    u16x8 o;
    o[0] = f2bf(v0.x); o[1] = f2bf(v0.y); o[2] = f2bf(v0.z); o[3] = f2bf(v0.w);
    o[4] = f2bf(v1.x); o[5] = f2bf(v1.y); o[6] = f2bf(v1.z); o[7] = f2bf(v1.w);
    int a1 = sA[2 * lt], a2 = sA[2 * lt + 1];
    *(u16x8*)(Xg + (size_t)a1 * DDIM + lane * 8) = o;
    *(u16x8*)(Xg + (size_t)a2 * DDIM + lane * 8) = o;
  }
}

// ========== GEMM1 mainloop: 128x128 tile, 4 waves (2x2), BK=32, =============
// ========== 2-PHASE DBUF, 32KB LDS -> 5 blocks/CU (20 waves), drain =========
// r3's proven structure, clean A/B vs r13's ring-3/48KB (3 blk/CU, 113.7us).
// m114: at >=3 blocks/CU cross-block overlap hides the drain; 5 > 3.
// Buf b (16KB at b*16384): A at 0 (128 rows x 64B), B at 8192.
// Per K-step: stage next buf (4 gload16) -> read frags (8 ds_read_b128) ->
// 16 MFMA -> __syncthreads (drains vmcnt+lgkm: next buf ready, cur re-usable).
template <int K>
__device__ __forceinline__ void mainloopD(
    const u16* __restrict__ aG0, const u16* __restrict__ aG1,
    const u16* __restrict__ bG0, const u16* __restrict__ bG1,
    char* ldsB, f32x4 (&acc)[4][4]) {
  const int tid = threadIdx.x;
  const int lane = tid & 63, wave = tid >> 6;
  const int wr = wave >> 1, wc = wave & 1;
  const int fr = lane & 15;
  const int slotx = ((lane >> 4) ^ ((lane >> 1) & 3)) & 3;
  const int frA = wr * 4096 + fr * 64 + slotx * 16;
  const int frB = 8192 + wc * 4096 + fr * 64 + slotx * 16;
  const int w1024 = wave * 1024;
  const int KT = K / 32;

  auto STAGE = [&](int u, int b) {
    const size_t go = (size_t)u * 32;
    char* base = ldsB + b * 16384 + w1024;
    gload16(aG0 + go, (u16*)base);
    gload16(aG1 + go, (u16*)(base + 4096));
    gload16(bG0 + go, (u16*)(base + 8192));
    gload16(bG1 + go, (u16*)(base + 8192 + 4096));
  };

  STAGE(0, 0);
  __syncthreads();
  int cur = 0;
#pragma unroll 1
  for (int ks = 0; ks < KT - 1; ++ks) {
    const int nb = cur ^ 1;
    STAGE(ks + 1, nb);                       // issue next-tile loads first
    const char* cb = ldsB + cur * 16384;
    short8 af[4], bf[4];
#pragma unroll
    for (int m = 0; m < 4; ++m)
      af[m] = *(const short8*)(cb + frA + m * 1024);
#pragma unroll
    for (int n = 0; n < 4; ++n)
      bf[n] = *(const short8*)(cb + frB + n * 1024);
    __builtin_amdgcn_s_setprio(1);
#pragma unroll
    for (int m = 0; m < 4; ++m)
#pragma unroll
      for (int n = 0; n < 4; ++n)
        acc[m][n] = __builtin_amdgcn_mfma_f32_16x16x32_bf16(af[m], bf[n],
                                                            acc[m][n], 0, 0, 0);
    __builtin_amdgcn_s_setprio(0);
    __syncthreads();                         // drains: next buf ready
    cur = nb;
  }
  {                                          // tail K-step
    const char* cb = ldsB + cur * 16384;
    short8 af[4], bf[4];
#pragma unroll
    for (int m = 0; m < 4; ++m)
      af[m] = *(const short8*)(cb + frA + m * 1024);
#pragma unroll
    for (int n = 0; n < 4; ++n)
      bf[n] = *(const short8*)(cb + frB + n * 1024);
#pragma unroll
    for (int m = 0; m < 4; ++m)
#pragma unroll
      for (int n = 0; n < 4; ++n)
        acc[m][n] = __builtin_amdgcn_mfma_f32_16x16x32_bf16(af[m], bf[n],
                                                            acc[m][n], 0, 0, 0);
  }
}

// ---------------- GEMM1: h = relu(Xg @ W1 + b1), bf16 out -------------------
__global__ __launch_bounds__(256) void gemm1_kernel(
    const u16* __restrict__ Xg, const u16* __restrict__ W1T,
    const float* __restrict__ b1, u16* __restrict__ h,
    const int* __restrict__ counts, const int* __restrict__ offsets,
    const int* __restrict__ tileE, const int* __restrict__ tileM,
    const int* __restrict__ nT) {
  __shared__ __align__(16) char ldsB[32768];
  int wg = blockIdx.x;
  int L = (wg & 7) * (G1GRID / 8) + (wg >> 3);   // XCD-chunked, ntile fastest
  int tile = L >> 4, ntile = L & 15;
  if (tile >= nT[0]) return;
  int e = tileE[tile], mtile = tileM[tile];
  int cnt = counts[e], off = offsets[e];
  int tid = threadIdx.x;
  int r0 = tid >> 2;
  int cswz = ((tid & 3) ^ ((tid >> 3) & 3)) * 8;
  const u16* Ap = Xg + (size_t)(off + mtile * 128) * DDIM;
  const u16* aG0 = Ap + (size_t)r0 * DDIM + cswz;
  const u16* aG1 = Ap + (size_t)(r0 + 64) * DDIM + cswz;
  const u16* Bp = W1T + ((size_t)e * FDIM + ntile * 128) * DDIM;
  const u16* bG0 = Bp + (size_t)r0 * DDIM + cswz;
  const u16* bG1 = Bp + (size_t)(r0 + 64) * DDIM + cswz;
  f32x4 acc[4][4] = {};
  mainloopD<DDIM>(aG0, aG1, bG0, bG1, ldsB, acc);
  int lane = tid & 63, wave = tid >> 6;
  int wr = wave >> 1, wc = wave & 1;
  int cl = lane & 15, rq = (lane >> 4) * 4;
#pragma unroll
  for (int m = 0; m < 4; ++m) {
#pragma unroll
    for (int i = 0; i < 4; ++i) {
      int gr = mtile * 128 + wr * 64 + m * 16 + rq + i;
      if (gr < cnt) {
#pragma unroll
        for (int n = 0; n < 4; ++n) {
          int gc = ntile * 128 + wc * 64 + n * 16 + cl;
          float v = acc[m][n][i] + b1[e * FDIM + gc];
          v = fmaxf(v, 0.f);
          h[(size_t)(off + gr) * FDIM + gc] = f2bf(v);
        }
      }
    }
  }
}

// ========== GEMM2 mainloop (r10/r13, proven): 128x128, ring-3, vmcnt(4) =====
template <int K>
__device__ __forceinline__ void mainloopR(
    const u16* __restrict__ aG0, const u16* __restrict__ aG1,
    const u16* __restrict__ bG0, const u16* __restrict__ bG1,
    char* ldsB, f32x4 (&acc)[4][4]) {
  const int tid = threadIdx.x;
  const int lane = tid & 63, wave = tid >> 6;
  const int wr = wave >> 1, wc = wave & 1;
  const int fr = lane & 15;
  const int slotx = ((lane >> 4) ^ ((lane >> 1) & 3)) & 3;
  const int frA = wr * 4096 + fr * 64 + slotx * 16;
  const int frB = 8192 + wc * 4096 + fr * 64 + slotx * 16;
  const int w1024 = wave * 1024;
  const int KT = K / 32;

  auto STAGE = [&](int u, int s) {
    const size_t go = (size_t)u * 32;
    char* base = ldsB + s * 16384 + w1024;
    gload16(aG0 + go, (u16*)base);
    gload16(aG1 + go, (u16*)(base + 4096));
    gload16(bG0 + go, (u16*)(base + 8192));
    gload16(bG1 + go, (u16*)(base + 8192 + 4096));
  };

  STAGE(0, 0);
  STAGE(1, 1);
  asm volatile("s_waitcnt vmcnt(4)" ::: "memory");
  __builtin_amdgcn_s_barrier();
  __builtin_amdgcn_sched_barrier(0);

  int s0 = 0, s1 = 1, s2 = 2;
#pragma unroll 1
  for (int t = 0; t < KT; ++t) {
    const char* cb = ldsB + s0 * 16384;
    short8 af[4], bf[4];
#pragma unroll
    for (int m = 0; m < 4; ++m)
      af[m] = *(const short8*)(cb + frA + m * 1024);
#pragma unroll
    for (int n = 0; n < 4; ++n)
      bf[n] = *(const short8*)(cb + frB + n * 1024);
    STAGE((t + 2) & (KT - 1), s2);
    asm volatile("s_waitcnt vmcnt(4)" ::: "memory");
    __builtin_amdgcn_s_barrier();
    __builtin_amdgcn_sched_barrier(0);
    __builtin_amdgcn_s_setprio(1);
#pragma unroll
    for (int m = 0; m < 4; ++m)
#pragma unroll
      for (int n = 0; n < 4; ++n)
        acc[m][n] = __builtin_amdgcn_mfma_f32_16x16x32_bf16(af[m], bf[n],
                                                            acc[m][n], 0, 0, 0);
    __builtin_amdgcn_s_setprio(0);
    __builtin_amdgcn_s_barrier();
    __builtin_amdgcn_sched_barrier(0);
    int tmp = s0; s0 = s1; s1 = s2; s2 = tmp;
  }
}

// ---------------- GEMM2: z[a] = w_a * (h @ W2 + b2), bf16 -------------------
__global__ __launch_bounds__(256) void gemm2_kernel(
    const u16* __restrict__ h, const u16* __restrict__ W2T,
    const float* __restrict__ b2, const float* __restrict__ assignW,
    const int* __restrict__ counts, const int* __restrict__ offsets,
    const int* __restrict__ tileE, const int* __restrict__ tileM,
    const int* __restrict__ nT, u16* __restrict__ z) {
  __shared__ __align__(16) char ldsB[49152];
  int wg = blockIdx.x;
  int L = (wg & 7) * (G2GRID / 8) + (wg >> 3);
  int tile = L >> 2, ntile = L & 3;
  if (tile >= nT[0]) return;
  int e = tileE[tile], mtile = tileM[tile];
  int cnt = counts[e], off = offsets[e];
  int tid = threadIdx.x;
  int r0 = tid >> 2;
  int cswz = ((tid & 3) ^ ((tid >> 3) & 3)) * 8;
  const u16* Ap = h + (size_t)(off + mtile * 128) * FDIM;
  const u16* aG0 = Ap + (size_t)r0 * FDIM + cswz;
  const u16* aG1 = Ap + (size_t)(r0 + 64) * FDIM + cswz;
  const u16* Bp = W2T + ((size_t)e * DDIM + ntile * 128) * FDIM;
  const u16* bG0 = Bp + (size_t)r0 * FDIM + cswz;
  const u16* bG1 = Bp + (size_t)(r0 + 64) * FDIM + cswz;
  f32x4 acc[4][4] = {};
  mainloopR<FDIM>(aG0, aG1, bG0, bG1, ldsB, acc);
  int lane = tid & 63, wave = tid >> 6;
  int wr = wave >> 1, wc = wave & 1;
  int cl = lane & 15, rq = (lane >> 4) * 4;
#pragma unroll
  for (int m = 0; m < 4; ++m) {
#pragma unroll
    for (int i = 0; i < 4; ++i) {
      int gr = mtile * 128 + wr * 64 + m * 16 + rq + i;
      if (gr < cnt) {
        int a = off + gr;
        float w = assignW[a];
#pragma unroll
        for (int n = 0; n < 4; ++n) {
          int gc = ntile * 128 + wc * 64 + n * 16 + cl;
          float v = (acc[m][n][i] + b2[e * DDIM + gc]) * w;
          z[(size_t)a * DDIM + gc] = f2bf(v);
        }
      }
    }
  }
}

// ---------------- combine: out[t] = z[a1(t)] + z[a2(t)] ---------------------
__global__ __launch_bounds__(256) void combine_kernel(
    const u16* __restrict__ z, const int* __restrict__ tokA,
    float* __restrict__ out) {
  int tid = threadIdx.x, wave = tid >> 6, lane = tid & 63;
  int t = blockIdx.x * 4 + wave;
  int a1 = tokA[2 * t], a2 = tokA[2 * t + 1];
  u16x8 v1 = *(const u16x8*)(z + (size_t)a1 * DDIM + lane * 8);
  u16x8 v2 = *(const u16x8*)(z + (size_t)a2 * DDIM + lane * 8);
  float4 o0, o1;
  o0.x = bf2f(v1[0]) + bf2f(v2[0]);
  o0.y = bf2f(v1[1]) + bf2f(v2[1]);
  o0.z = bf2f(v1[2]) + bf2f(v2[2]);
  o0.w = bf2f(v1[3]) + bf2f(v2[3]);
  o1.x = bf2f(v1[4]) + bf2f(v2[4]);
  o1.y = bf2f(v1[5]) + bf2f(v2[5]);
  o1.z = bf2f(v1[6]) + bf2f(v2[6]);
  o1.w = bf2f(v1[7]) + bf2f(v2[7]);
  float4* o = (float4*)(out + (size_t)t * DDIM + lane * 8);
  o[0] = o0;
  o[1] = o1;
}

extern "C" void kernel_launch(void* const* d_in, const int* in_sizes, int n_in,
                              void* d_out, int out_size, void* d_ws, size_t ws_size,
                              hipStream_t stream) {
  const float* x  = (const float*)d_in[0];
  const float* Wr = (const float*)d_in[1];
  const float* br = (const float*)d_in[2];
  const float* W1 = (const float*)d_in[3];
  const float* b1 = (const float*)d_in[4];
  const float* W2 = (const float*)d_in[5];
  const float* b2 = (const float*)d_in[6];
  float* out = (float*)d_out;

  char* ws = (char*)d_ws;
  size_t p = 0;
  auto alloc = [&](size_t bytes) -> void* {
    void* r = ws + p;
    p = (p + bytes + 255) & ~(size_t)255;
    return r;
  };
  int* counts     = (int*)alloc(ENUM * 4);
  int* offsets    = (int*)alloc(ENUM * 4);
  int* nT         = (int*)alloc(4);
  int* tileE      = (int*)alloc(NTCAP * 4);
  int* tileM      = (int*)alloc(NTCAP * 4);
  int* top2e      = (int*)alloc((size_t)NTOK * 2 * 4);
  float* top2v    = (float*)alloc((size_t)NTOK * 2 * 4);
  int* tokA       = (int*)alloc((size_t)NTOK * 2 * 4);  // token -> assignment
  float* assignW  = (float*)alloc((size_t)APAD * 4);
  int* histBase   = (int*)alloc((size_t)NBLK * 8 * 4);
  float* gatePart = (float*)alloc((size_t)NBLK * 8 * 4);
  u16* W1T        = (u16*)alloc((size_t)ENUM * FDIM * DDIM * 2);
  u16* W2T        = (u16*)alloc((size_t)ENUM * DDIM * FDIM * 2);
  u16* Xg         = (u16*)alloc((size_t)APAD * DDIM * 2);
  u16* hbuf       = (u16*)alloc((size_t)APAD * FDIM * 2);
  u16* z          = Xg;   // alias: Xg dead after gemm1
  (void)in_sizes; (void)n_in; (void)out_size; (void)ws_size;  // ~203 MB used

  prep_kernel<<<NBLK + 4096, 256, 0, stream>>>(x, Wr, br, top2e, top2v,
                                               histBase, gatePart, W1, W2,
                                               W1T, W2T);
  scan_kernel<<<1, 256, 0, stream>>>(histBase, gatePart, offsets, counts,
                                     tileE, tileM, nT,
                                     out + (size_t)NTOK * DDIM);
  place_kernel<<<NBLK, 256, 0, stream>>>(x, top2e, top2v, histBase, offsets,
                                         tokA, assignW, Xg);
  gemm1_kernel<<<G1GRID, 256, 0, stream>>>(
      Xg, W1T, b1, hbuf, counts, offsets, tileE, tileM, nT);
  gemm2_kernel<<<G2GRID, 256, 0, stream>>>(
      hbuf, W2T, b2, assignW, counts, offsets, tileE, tileM, nT, z);
  combine_kernel<<<NTOK / 4, 256, 0, stream>>>(z, tokA, out);
}